// Round 1
// baseline (356.677 us; speedup 1.0000x reference)
//
#include <hip/hip_runtime.h>

#define LOG2E 1.44269504088896f
#define LN2   0.693147180559945f

__device__ __forceinline__ float fast_sigmoid(float v) {
    // 1/(1+exp(-v)) = rcp(1 + exp2(-v*log2e))
    return __builtin_amdgcn_rcpf(1.0f + __builtin_amdgcn_exp2f(-v * LOG2E));
}

// W_h [H,D] -> W_t [D,H]
__global__ void transpose_kernel(const float* __restrict__ Wh,
                                 float* __restrict__ Wt, int Hn, int Dn) {
    __shared__ float tile[32][33];
    int tx = threadIdx.x;        // 0..31
    int ty = threadIdx.y;        // 0..7
    int i0 = blockIdx.x * 32;    // D tile origin
    int h0 = blockIdx.y * 32;    // H tile origin
#pragma unroll
    for (int k = 0; k < 4; ++k) {
        tile[ty + 8 * k][tx] = Wh[(h0 + ty + 8 * k) * Dn + (i0 + tx)];
    }
    __syncthreads();
#pragma unroll
    for (int k = 0; k < 4; ++k) {
        Wt[(i0 + ty + 8 * k) * Hn + (h0 + tx)] = tile[tx][ty + 8 * k];
    }
}

template <bool USE_WT>
__global__ __launch_bounds__(64) void nade_kernel(
    const float* __restrict__ x,    // [B,D]
    const float* __restrict__ Wt,   // [D,H] transposed (if USE_WT)
    const float* __restrict__ Wh,   // [H,D] original (fallback)
    const float* __restrict__ bh,   // [H]
    const float* __restrict__ aw,   // [D,H]
    const float* __restrict__ ab,   // [D]
    float* __restrict__ out,        // [B]
    int Dn, int Hn)
{
    const int b    = blockIdx.x;    // one batch row per 64-thread block (1 wave)
    const int lane = threadIdx.x;   // 0..63, owns h = 4*lane .. 4*lane+3
    const float* xrow = x + (size_t)b * Dn;

    const float4 bh4 = *(const float4*)(bh + lane * 4);
    float4 acc = make_float4(0.f, 0.f, 0.f, 0.f);
    float ll = 0.f;

#pragma unroll 4
    for (int i = 0; i < Dn; ++i) {
        const float4 aw4 = *(const float4*)(aw + (size_t)i * Hn + lane * 4);
        float4 w4;
        if (USE_WT) {
            w4 = *(const float4*)(Wt + (size_t)i * Hn + lane * 4);
        } else {
            w4.x = Wh[(size_t)(lane * 4 + 0) * Dn + i];
            w4.y = Wh[(size_t)(lane * 4 + 1) * Dn + i];
            w4.z = Wh[(size_t)(lane * 4 + 2) * Dn + i];
            w4.w = Wh[(size_t)(lane * 4 + 3) * Dn + i];
        }

        // exclusive prefix: hidden uses acc BEFORE the step-i update
        float p = aw4.x * fast_sigmoid(acc.x);
        p += aw4.y * fast_sigmoid(acc.y);
        p += aw4.z * fast_sigmoid(acc.z);
        p += aw4.w * fast_sigmoid(acc.w);

        // 64-lane butterfly reduction (result uniform in every lane)
#pragma unroll
        for (int off = 32; off > 0; off >>= 1)
            p += __shfl_xor(p, off, 64);

        const float s = p + ab[i];
        // log(sigmoid(s)) = -ln(1 + e^-s)
        const float lp = -LN2 *
            __builtin_amdgcn_logf(1.0f + __builtin_amdgcn_exp2f(-s * LOG2E));

        const float xv = xrow[i];
        ll += xv * lp + (1.0f - xv) * (1.0f - lp);

        acc.x += xv * w4.x + bh4.x;
        acc.y += xv * w4.y + bh4.y;
        acc.z += xv * w4.z + bh4.z;
        acc.w += xv * w4.w + bh4.w;
    }

    if (lane == 0) out[b] = ll;
}

extern "C" void kernel_launch(void* const* d_in, const int* in_sizes, int n_in,
                              void* d_out, int out_size, void* d_ws, size_t ws_size,
                              hipStream_t stream) {
    const float* x  = (const float*)d_in[0];
    const float* Wh = (const float*)d_in[1];
    const float* bh = (const float*)d_in[2];
    const float* aw = (const float*)d_in[3];
    const float* ab = (const float*)d_in[4];
    float* out = (float*)d_out;

    const int Bn = out_size;          // 1024
    const int Hn = in_sizes[2];       // 256
    const int Dn = in_sizes[4];       // 1024

    const size_t wt_bytes = (size_t)Dn * Hn * sizeof(float);
    const bool use_wt = ws_size >= wt_bytes && (Dn % 32 == 0) && (Hn % 32 == 0);

    if (use_wt) {
        float* Wt = (float*)d_ws;
        transpose_kernel<<<dim3(Dn / 32, Hn / 32), dim3(32, 8), 0, stream>>>(
            Wh, Wt, Hn, Dn);
        nade_kernel<true><<<Bn, 64, 0, stream>>>(x, Wt, Wh, bh, aw, ab, out, Dn, Hn);
    } else {
        nade_kernel<false><<<Bn, 64, 0, stream>>>(x, nullptr, Wh, bh, aw, ab, out, Dn, Hn);
    }
}

// Round 2
// 164.404 us; speedup vs baseline: 2.1695x; 2.1695x over previous
//
#include <hip/hip_runtime.h>

#define LOG2E 1.44269504088896f
#define LN2   0.693147180559945f

__device__ __forceinline__ float fast_sigmoid(float v) {
    // 1/(1+exp(-v)) = rcp(1 + exp2(-v*log2e))
    return __builtin_amdgcn_rcpf(1.0f + __builtin_amdgcn_exp2f(-v * LOG2E));
}

// ---------- W_h [H,D] -> W_t [D,H] ----------
__global__ void transpose_kernel(const float* __restrict__ Wh,
                                 float* __restrict__ Wt, int Hn, int Dn) {
    __shared__ float tile[32][33];
    int tx = threadIdx.x;        // 0..31
    int ty = threadIdx.y;        // 0..7
    int i0 = blockIdx.x * 32;    // D tile origin
    int h0 = blockIdx.y * 32;    // H tile origin
#pragma unroll
    for (int k = 0; k < 4; ++k)
        tile[ty + 8 * k][tx] = Wh[(size_t)(h0 + ty + 8 * k) * Dn + (i0 + tx)];
    __syncthreads();
#pragma unroll
    for (int k = 0; k < 4; ++k)
        Wt[(size_t)(i0 + ty + 8 * k) * Hn + (h0 + tx)] = tile[tx][ty + 8 * k];
}

// ---------- pass 1: per-chunk partial x·W sums ----------
// partial[b][c][h] = sum_{i in chunk c} x[b,i] * Wt[i,h]
__global__ __launch_bounds__(256) void partial_kernel(
    const float* __restrict__ x, const float* __restrict__ Wt,
    float* __restrict__ partial, int Dn, int Hn, int Bn, int C, int L)
{
    const int gw   = blockIdx.x * 4 + (threadIdx.x >> 6);
    const int lane = threadIdx.x & 63;
    const int b = gw % Bn;           // c-major: co-resident waves share rows
    const int c = gw / Bn;
    const float* xrow = x + (size_t)b * Dn;

    float4 acc = make_float4(0.f, 0.f, 0.f, 0.f);
    const int i0 = c * L;
#pragma unroll 4
    for (int i = i0; i < i0 + L; ++i) {
        const float xv = xrow[i];
        const float4 w4 = *(const float4*)(Wt + (size_t)i * Hn + lane * 4);
        acc.x += xv * w4.x;
        acc.y += xv * w4.y;
        acc.z += xv * w4.z;
        acc.w += xv * w4.w;
    }
    *(float4*)(partial + ((size_t)b * C + c) * Hn + lane * 4) = acc;
}

// ---------- pass 2: exclusive scan over chunks (in place) ----------
__global__ __launch_bounds__(256) void scan_kernel(
    float* __restrict__ partial, int Hn, int C)
{
    const int b    = blockIdx.x * 4 + (threadIdx.x >> 6);
    const int lane = threadIdx.x & 63;
    float* base = partial + (size_t)b * C * Hn + lane * 4;
    float4 acc = make_float4(0.f, 0.f, 0.f, 0.f);
    for (int c = 0; c < C; ++c) {
        float4 cur = *(float4*)(base + (size_t)c * Hn);
        *(float4*)(base + (size_t)c * Hn) = acc;
        acc.x += cur.x; acc.y += cur.y; acc.z += cur.z; acc.w += cur.w;
    }
}

// ---------- pass 3: main NADE chunk kernel ----------
__global__ __launch_bounds__(256) void nade_main(
    const float* __restrict__ x,      // [B,D]
    const float* __restrict__ Wt,     // [D,H]
    const float* __restrict__ prefix, // [B,C,H] exclusive x·W prefix
    const float* __restrict__ bh,     // [H]
    const float* __restrict__ aw,     // [D,H]
    const float* __restrict__ ab,     // [D]
    float* __restrict__ llp,          // [B,C] partial log-likelihoods
    int Dn, int Hn, int Bn, int C, int L)
{
    const int gw   = blockIdx.x * 4 + (threadIdx.x >> 6);
    const int lane = threadIdx.x & 63;
    const int b = gw % Bn;           // c-major mapping
    const int c = gw / Bn;
    const float* xrow = x + (size_t)b * Dn;

    const float4 bh4 = *(const float4*)(bh + lane * 4);
    float4 acc = *(const float4*)(prefix + ((size_t)b * C + c) * Hn + lane * 4);
    const float cl = (float)(c * L);       // analytic i*b_h term at chunk start
    acc.x += cl * bh4.x;
    acc.y += cl * bh4.y;
    acc.z += cl * bh4.z;
    acc.w += cl * bh4.w;

    float ll = 0.f;
    const int i0 = c * L;
#pragma unroll 4
    for (int i = i0; i < i0 + L; ++i) {
        const float4 aw4 = *(const float4*)(aw + (size_t)i * Hn + lane * 4);
        const float4 w4  = *(const float4*)(Wt + (size_t)i * Hn + lane * 4);

        // exclusive prefix: hidden uses acc BEFORE the step-i update
        float p = aw4.x * fast_sigmoid(acc.x);
        p += aw4.y * fast_sigmoid(acc.y);
        p += aw4.z * fast_sigmoid(acc.z);
        p += aw4.w * fast_sigmoid(acc.w);

#pragma unroll
        for (int off = 32; off > 0; off >>= 1)
            p += __shfl_xor(p, off, 64);

        const float s = p + ab[i];
        // log(sigmoid(s)) = -ln(1 + e^-s)
        const float lp = -LN2 *
            __builtin_amdgcn_logf(1.0f + __builtin_amdgcn_exp2f(-s * LOG2E));

        const float xv = xrow[i];
        ll += xv * lp + (1.0f - xv) * (1.0f - lp);

        acc.x += xv * w4.x + bh4.x;
        acc.y += xv * w4.y + bh4.y;
        acc.z += xv * w4.z + bh4.z;
        acc.w += xv * w4.w + bh4.w;
    }

    if (lane == 0) llp[(size_t)b * C + c] = ll;
}

// ---------- pass 4: final reduce ----------
__global__ void final_kernel(const float* __restrict__ llp,
                             float* __restrict__ out, int Bn, int C) {
    const int b = blockIdx.x * blockDim.x + threadIdx.x;
    if (b < Bn) {
        float s = 0.f;
        for (int c = 0; c < C; ++c) s += llp[(size_t)b * C + c];
        out[b] = s;
    }
}

// ---------- fallback (round-1 kernel) ----------
template <bool USE_WT>
__global__ __launch_bounds__(64) void nade_kernel(
    const float* __restrict__ x, const float* __restrict__ Wt,
    const float* __restrict__ Wh, const float* __restrict__ bh,
    const float* __restrict__ aw, const float* __restrict__ ab,
    float* __restrict__ out, int Dn, int Hn)
{
    const int b    = blockIdx.x;
    const int lane = threadIdx.x;
    const float* xrow = x + (size_t)b * Dn;
    const float4 bh4 = *(const float4*)(bh + lane * 4);
    float4 acc = make_float4(0.f, 0.f, 0.f, 0.f);
    float ll = 0.f;
#pragma unroll 4
    for (int i = 0; i < Dn; ++i) {
        const float4 aw4 = *(const float4*)(aw + (size_t)i * Hn + lane * 4);
        float4 w4;
        if (USE_WT) {
            w4 = *(const float4*)(Wt + (size_t)i * Hn + lane * 4);
        } else {
            w4.x = Wh[(size_t)(lane * 4 + 0) * Dn + i];
            w4.y = Wh[(size_t)(lane * 4 + 1) * Dn + i];
            w4.z = Wh[(size_t)(lane * 4 + 2) * Dn + i];
            w4.w = Wh[(size_t)(lane * 4 + 3) * Dn + i];
        }
        float p = aw4.x * fast_sigmoid(acc.x);
        p += aw4.y * fast_sigmoid(acc.y);
        p += aw4.z * fast_sigmoid(acc.z);
        p += aw4.w * fast_sigmoid(acc.w);
#pragma unroll
        for (int off = 32; off > 0; off >>= 1)
            p += __shfl_xor(p, off, 64);
        const float s = p + ab[i];
        const float lp = -LN2 *
            __builtin_amdgcn_logf(1.0f + __builtin_amdgcn_exp2f(-s * LOG2E));
        const float xv = xrow[i];
        ll += xv * lp + (1.0f - xv) * (1.0f - lp);
        acc.x += xv * w4.x + bh4.x;
        acc.y += xv * w4.y + bh4.y;
        acc.z += xv * w4.z + bh4.z;
        acc.w += xv * w4.w + bh4.w;
    }
    if (lane == 0) out[b] = ll;
}

extern "C" void kernel_launch(void* const* d_in, const int* in_sizes, int n_in,
                              void* d_out, int out_size, void* d_ws, size_t ws_size,
                              hipStream_t stream) {
    const float* x  = (const float*)d_in[0];
    const float* Wh = (const float*)d_in[1];
    const float* bh = (const float*)d_in[2];
    const float* aw = (const float*)d_in[3];
    const float* ab = (const float*)d_in[4];
    float* out = (float*)d_out;

    const int Bn = out_size;          // 1024
    const int Hn = in_sizes[2];       // 256
    const int Dn = in_sizes[4];       // 1024
    const int C  = 8;
    const int L  = Dn / C;

    const size_t wt_bytes  = (size_t)Dn * Hn * sizeof(float);
    const size_t pf_bytes  = (size_t)Bn * C * Hn * sizeof(float);
    const size_t llp_bytes = (size_t)Bn * C * sizeof(float);

    const bool shapes_ok = (Hn == 256) && (Dn % (32 * C) == 0) && (Bn % 4 == 0);
    const bool full_path = shapes_ok && ws_size >= wt_bytes + pf_bytes + llp_bytes;

    if (full_path) {
        float* Wt     = (float*)d_ws;
        float* prefix = (float*)((char*)d_ws + wt_bytes);
        float* llp    = (float*)((char*)d_ws + wt_bytes + pf_bytes);

        transpose_kernel<<<dim3(Dn / 32, Hn / 32), dim3(32, 8), 0, stream>>>(
            Wh, Wt, Hn, Dn);
        partial_kernel<<<(Bn * C) / 4, 256, 0, stream>>>(
            x, Wt, prefix, Dn, Hn, Bn, C, L);
        scan_kernel<<<Bn / 4, 256, 0, stream>>>(prefix, Hn, C);
        nade_main<<<(Bn * C) / 4, 256, 0, stream>>>(
            x, Wt, prefix, bh, aw, ab, llp, Dn, Hn, Bn, C, L);
        final_kernel<<<(Bn + 255) / 256, 256, 0, stream>>>(llp, out, Bn, C);
    } else if (ws_size >= wt_bytes && (Dn % 32 == 0) && (Hn % 32 == 0) && Hn == 256) {
        float* Wt = (float*)d_ws;
        transpose_kernel<<<dim3(Dn / 32, Hn / 32), dim3(32, 8), 0, stream>>>(
            Wh, Wt, Hn, Dn);
        nade_kernel<true><<<Bn, 64, 0, stream>>>(x, Wt, Wh, bh, aw, ab, out, Dn, Hn);
    } else {
        nade_kernel<false><<<Bn, 64, 0, stream>>>(x, nullptr, Wh, bh, aw, ab, out, Dn, Hn);
    }
}

// Round 3
// 144.096 us; speedup vs baseline: 2.4753x; 1.1409x over previous
//
#include <hip/hip_runtime.h>

#define LOG2E  1.44269504088896f
#define NLOG2E (-1.44269504088896f)
#define LN2    0.693147180559945f

// ---------- W_h [H,D] -> W_t [D,H] (optionally pre-scaled by `scale`) ----------
__global__ void transpose_kernel(const float* __restrict__ Wh,
                                 float* __restrict__ Wt, int Hn, int Dn,
                                 float scale) {
    __shared__ float tile[32][33];
    int tx = threadIdx.x;        // 0..31
    int ty = threadIdx.y;        // 0..7
    int i0 = blockIdx.x * 32;    // D tile origin
    int h0 = blockIdx.y * 32;    // H tile origin
#pragma unroll
    for (int k = 0; k < 4; ++k)
        tile[ty + 8 * k][tx] = scale * Wh[(size_t)(h0 + ty + 8 * k) * Dn + (i0 + tx)];
    __syncthreads();
#pragma unroll
    for (int k = 0; k < 4; ++k)
        Wt[(size_t)(i0 + ty + 8 * k) * Hn + (h0 + tx)] = tile[tx][ty + 8 * k];
}

// ---------- pass 1: per-chunk partial x·W sums (scaled domain) ----------
__global__ __launch_bounds__(256) void partial_kernel(
    const float* __restrict__ x, const float* __restrict__ Wt,
    float* __restrict__ partial, int Dn, int Hn, int Bn, int C, int L)
{
    const int gw   = blockIdx.x * 4 + (threadIdx.x >> 6);
    const int lane = threadIdx.x & 63;
    const int b = gw % Bn;           // c-major: co-resident waves share rows
    const int c = gw / Bn;
    const float* xrow = x + (size_t)b * Dn;

    float4 acc = make_float4(0.f, 0.f, 0.f, 0.f);
    const int i0 = c * L;
#pragma unroll 4
    for (int i = i0; i < i0 + L; ++i) {
        const float xv = xrow[i];
        const float4 w4 = *(const float4*)(Wt + (size_t)i * Hn + lane * 4);
        acc.x += xv * w4.x;
        acc.y += xv * w4.y;
        acc.z += xv * w4.z;
        acc.w += xv * w4.w;
    }
    *(float4*)(partial + ((size_t)b * C + c) * Hn + lane * 4) = acc;
}

// ---------- pass 2: exclusive scan over chunks (in place) ----------
__global__ __launch_bounds__(256) void scan_kernel(
    float* __restrict__ partial, int Hn, int C)
{
    const int b    = blockIdx.x * 4 + (threadIdx.x >> 6);
    const int lane = threadIdx.x & 63;
    float* base = partial + (size_t)b * C * Hn + lane * 4;
    float4 acc = make_float4(0.f, 0.f, 0.f, 0.f);
    for (int c = 0; c < C; ++c) {
        float4 cur = *(float4*)(base + (size_t)c * Hn);
        *(float4*)(base + (size_t)c * Hn) = acc;
        acc.x += cur.x; acc.y += cur.y; acc.z += cur.z; acc.w += cur.w;
    }
}

// ---------- pass 3: main NADE chunk kernel (batched-4i) ----------
// Scaled domain: Wt2 = -log2e * W^T, prefix likewise, bh2 = -log2e * b_h.
// sigmoid(acc) = rcp(1 + exp2(accw2 + i * bh2))
__global__ __launch_bounds__(256) void nade_main(
    const float* __restrict__ x,      // [B,D]
    const float* __restrict__ Wt2,    // [D,H] transposed, scaled
    const float* __restrict__ prefix, // [B,C,H] exclusive prefix, scaled
    const float* __restrict__ bh,     // [H] (unscaled)
    const float* __restrict__ aw,     // [D,H]
    const float* __restrict__ ab,     // [D]
    float* __restrict__ llp,          // [B,C] partial log-likelihoods
    int Dn, int Hn, int Bn, int C, int L)
{
    const int gw   = blockIdx.x * 4 + (threadIdx.x >> 6);
    const int lane = threadIdx.x & 63;
    const int b = gw % Bn;           // c-major mapping
    const int c = gw / Bn;
    const float* xrow = x + (size_t)b * Dn;
    const int j = lane & 3;          // this lane's i-class within a 4-batch

    float4 bh2 = *(const float4*)(bh + lane * 4);
    bh2.x *= NLOG2E; bh2.y *= NLOG2E; bh2.z *= NLOG2E; bh2.w *= NLOG2E;

    float4 accw2 = *(const float4*)(prefix + ((size_t)b * C + c) * Hn + lane * 4);
    float i_f = (float)(c * L);      // global i (bias count), folded via fma

    float A = 0.f;                   // sum of lp*(2*x-1) over my i-class
    float Bs = 0.f;                  // sum of x over my i-class
    const int i0 = c * L;

    for (int i = i0; i < i0 + L; i += 4) {
        float p[4];
        const float xq  = xrow[i + j];   // per-lane: x for my i-class
        const float abq = ab[i + j];     // per-lane: alpha_bias for my i-class
#pragma unroll
        for (int m = 0; m < 4; ++m) {
            const float4 aw4 = *(const float4*)(aw  + (size_t)(i + m) * Hn + lane * 4);
            const float4 w4  = *(const float4*)(Wt2 + (size_t)(i + m) * Hn + lane * 4);
            // hidden uses state BEFORE update m (exclusive prefix)
            const float s0 = __builtin_amdgcn_rcpf(
                1.0f + __builtin_amdgcn_exp2f(fmaf(i_f, bh2.x, accw2.x)));
            const float s1 = __builtin_amdgcn_rcpf(
                1.0f + __builtin_amdgcn_exp2f(fmaf(i_f, bh2.y, accw2.y)));
            const float s2 = __builtin_amdgcn_rcpf(
                1.0f + __builtin_amdgcn_exp2f(fmaf(i_f, bh2.z, accw2.z)));
            const float s3 = __builtin_amdgcn_rcpf(
                1.0f + __builtin_amdgcn_exp2f(fmaf(i_f, bh2.w, accw2.w)));
            float pm = aw4.x * s0;
            pm = fmaf(aw4.y, s1, pm);
            pm = fmaf(aw4.z, s2, pm);
            pm = fmaf(aw4.w, s3, pm);
            p[m] = pm;
            // state update (scaled domain, bias handled analytically via i_f)
            const float xv = xrow[i + m];
            accw2.x = fmaf(xv, w4.x, accw2.x);
            accw2.y = fmaf(xv, w4.y, accw2.y);
            accw2.z = fmaf(xv, w4.z, accw2.z);
            accw2.w = fmaf(xv, w4.w, accw2.w);
            i_f += 1.0f;
        }
        // batched reduce: sum bits {0,1,4,5} of lane for each p[m]
#pragma unroll
        for (int m = 0; m < 4; ++m) {
            p[m] += __shfl_xor(p[m], 1, 64);
            p[m] += __shfl_xor(p[m], 2, 64);
            p[m] += __shfl_xor(p[m], 16, 64);
            p[m] += __shfl_xor(p[m], 32, 64);
        }
        // select my class's value (bits {0,1} index j), then sum bits {2,3}
        float t0 = (lane & 1) ? p[1] : p[0];
        float t1 = (lane & 1) ? p[3] : p[2];
        float q  = (lane & 2) ? t1 : t0;
        q += __shfl_xor(q, 4, 64);
        q += __shfl_xor(q, 8, 64);
        // q = full 256-h dot product for i + j (replicated over 16 lanes)
        const float s = q + abq;
        // lp = log(sigmoid(s)) = -ln(1 + e^-s)
        const float lp = -LN2 *
            __builtin_amdgcn_logf(1.0f + __builtin_amdgcn_exp2f(-s * LOG2E));
        // term = 2*x*lp - x - lp + 1 ; accumulate A=sum lp*(2x-1), B=sum x
        A = fmaf(lp, fmaf(2.0f, xq, -1.0f), A);
        Bs += xq;
    }

    // each class replicated 16x across the wave
#pragma unroll
    for (int off = 32; off > 0; off >>= 1) {
        A  += __shfl_xor(A, off, 64);
        Bs += __shfl_xor(Bs, off, 64);
    }
    if (lane == 0)
        llp[(size_t)b * C + c] = (A - Bs) * (1.0f / 16.0f) + (float)L;
}

// ---------- pass 4: final reduce ----------
__global__ void final_kernel(const float* __restrict__ llp,
                             float* __restrict__ out, int Bn, int C) {
    const int b = blockIdx.x * blockDim.x + threadIdx.x;
    if (b < Bn) {
        float s = 0.f;
        for (int c = 0; c < C; ++c) s += llp[(size_t)b * C + c];
        out[b] = s;
    }
}

// ---------- fallback (round-1 style, unscaled) ----------
__global__ __launch_bounds__(64) void nade_fallback(
    const float* __restrict__ x, const float* __restrict__ Wh,
    const float* __restrict__ bh, const float* __restrict__ aw,
    const float* __restrict__ ab, float* __restrict__ out, int Dn, int Hn)
{
    const int b    = blockIdx.x;
    const int lane = threadIdx.x;
    const int nper = (Hn + 255) / 256 * 4;  // h's per lane (generic-ish)
    const float* xrow = x + (size_t)b * Dn;
    float ll = 0.f;
    // simple scalar version (correct for any H multiple of 64)
    float accl[8];
    float bhl[8];
    for (int k = 0; k < 8; ++k) { accl[k] = 0.f; bhl[k] = 0.f; }
    const int hper = Hn / 64;
    for (int k = 0; k < hper && k < 8; ++k) bhl[k] = bh[lane * hper + k];
    for (int i = 0; i < Dn; ++i) {
        float pm = 0.f;
        for (int k = 0; k < hper && k < 8; ++k) {
            const int h = lane * hper + k;
            const float sg = __builtin_amdgcn_rcpf(
                1.0f + __builtin_amdgcn_exp2f(-accl[k] * LOG2E));
            pm = fmaf(aw[(size_t)i * Hn + h], sg, pm);
        }
        for (int off = 32; off > 0; off >>= 1) pm += __shfl_xor(pm, off, 64);
        const float s = pm + ab[i];
        const float lp = -LN2 *
            __builtin_amdgcn_logf(1.0f + __builtin_amdgcn_exp2f(-s * LOG2E));
        const float xv = xrow[i];
        ll += xv * lp + (1.0f - xv) * (1.0f - lp);
        for (int k = 0; k < hper && k < 8; ++k) {
            const int h = lane * hper + k;
            accl[k] = fmaf(xv, Wh[(size_t)h * Dn + i], accl[k]) + bhl[k];
        }
    }
    if (lane == 0) out[b] = ll;
    (void)nper;
}

extern "C" void kernel_launch(void* const* d_in, const int* in_sizes, int n_in,
                              void* d_out, int out_size, void* d_ws, size_t ws_size,
                              hipStream_t stream) {
    const float* x  = (const float*)d_in[0];
    const float* Wh = (const float*)d_in[1];
    const float* bh = (const float*)d_in[2];
    const float* aw = (const float*)d_in[3];
    const float* ab = (const float*)d_in[4];
    float* out = (float*)d_out;

    const int Bn = out_size;          // 1024
    const int Hn = in_sizes[2];       // 256
    const int Dn = in_sizes[4];       // 1024
    const int C  = 8;
    const int L  = Dn / C;

    const size_t wt_bytes  = (size_t)Dn * Hn * sizeof(float);
    const size_t pf_bytes  = (size_t)Bn * C * Hn * sizeof(float);
    const size_t llp_bytes = (size_t)Bn * C * sizeof(float);

    const bool shapes_ok = (Hn == 256) && (Dn % (32 * C) == 0) && (L % 4 == 0) &&
                           (Bn % 4 == 0);
    const bool full_path = shapes_ok && ws_size >= wt_bytes + pf_bytes + llp_bytes;

    if (full_path) {
        float* Wt2    = (float*)d_ws;
        float* prefix = (float*)((char*)d_ws + wt_bytes);
        float* llp    = (float*)((char*)d_ws + wt_bytes + pf_bytes);

        transpose_kernel<<<dim3(Dn / 32, Hn / 32), dim3(32, 8), 0, stream>>>(
            Wh, Wt2, Hn, Dn, NLOG2E);
        partial_kernel<<<(Bn * C) / 4, 256, 0, stream>>>(
            x, Wt2, prefix, Dn, Hn, Bn, C, L);
        scan_kernel<<<Bn / 4, 256, 0, stream>>>(prefix, Hn, C);
        nade_main<<<(Bn * C) / 4, 256, 0, stream>>>(
            x, Wt2, prefix, bh, aw, ab, llp, Dn, Hn, Bn, C, L);
        final_kernel<<<(Bn + 255) / 256, 256, 0, stream>>>(llp, out, Bn, C);
    } else {
        nade_fallback<<<Bn, 64, 0, stream>>>(x, Wh, bh, aw, ab, out, Dn, Hn);
    }
}

// Round 4
// 140.732 us; speedup vs baseline: 2.5344x; 1.0239x over previous
//
#include <hip/hip_runtime.h>

#define LOG2E  1.44269504088896f
#define NLOG2E (-1.44269504088896f)
#define LN2    0.693147180559945f

// ---------- W_h [H,D] -> W_t [D,H] (pre-scaled by `scale`) ----------
__global__ void transpose_kernel(const float* __restrict__ Wh,
                                 float* __restrict__ Wt, int Hn, int Dn,
                                 float scale) {
    __shared__ float tile[32][33];
    int tx = threadIdx.x;        // 0..31
    int ty = threadIdx.y;        // 0..7
    int i0 = blockIdx.x * 32;    // D tile origin
    int h0 = blockIdx.y * 32;    // H tile origin
#pragma unroll
    for (int k = 0; k < 4; ++k)
        tile[ty + 8 * k][tx] = scale * Wh[(size_t)(h0 + ty + 8 * k) * Dn + (i0 + tx)];
    __syncthreads();
#pragma unroll
    for (int k = 0; k < 4; ++k)
        Wt[(size_t)(i0 + ty + 8 * k) * Hn + (h0 + tx)] = tile[tx][ty + 8 * k];
}

// ---------- pass 1: per-chunk partial x·W sums (scaled domain) ----------
__global__ __launch_bounds__(256) void partial_kernel(
    const float* __restrict__ x, const float* __restrict__ Wt,
    float* __restrict__ partial, int Dn, int Hn, int Bn, int C, int L)
{
    const int gw   = blockIdx.x * 4 + (threadIdx.x >> 6);
    const int lane = threadIdx.x & 63;
    const int b = gw % Bn;           // c-major: co-resident waves share rows
    const int c = gw / Bn;
    const float* xrow = x + (size_t)b * Dn;

    float4 acc = make_float4(0.f, 0.f, 0.f, 0.f);
    const int i0 = c * L;
#pragma unroll 4
    for (int i = i0; i < i0 + L; ++i) {
        const float xv = xrow[i];
        const float4 w4 = *(const float4*)(Wt + (size_t)i * Hn + lane * 4);
        acc.x += xv * w4.x;
        acc.y += xv * w4.y;
        acc.z += xv * w4.z;
        acc.w += xv * w4.w;
    }
    *(float4*)(partial + ((size_t)b * C + c) * Hn + lane * 4) = acc;
}

// ---------- pass 2: exclusive scan over chunks (in place) ----------
__global__ __launch_bounds__(256) void scan_kernel(
    float* __restrict__ partial, int Hn, int C)
{
    const int b    = blockIdx.x * 4 + (threadIdx.x >> 6);
    const int lane = threadIdx.x & 63;
    float* base = partial + (size_t)b * C * Hn + lane * 4;
    float4 acc = make_float4(0.f, 0.f, 0.f, 0.f);
    for (int c = 0; c < C; ++c) {
        float4 cur = *(float4*)(base + (size_t)c * Hn);
        *(float4*)(base + (size_t)c * Hn) = acc;
        acc.x += cur.x; acc.y += cur.y; acc.z += cur.z; acc.w += cur.w;
    }
}

// ---------- pass 3: main NADE chunk kernel ----------
// Scaled domain: Wt2 = -log2e * W^T, prefix likewise, bh2 = -log2e * b_h.
// sigma_h = 1/(1 + 2^{u_h}),  u_h = accw2_h + i * bh2_h  (clamped to +-30).
// Per lane-i, batch the 4 divisions into one rcp:
//   sum_k aw_k/(1+t_k) = N/D,  D = prod(1+t_k),  N = sum_k aw_k prod_{j!=k}(1+t_j)
__global__ __launch_bounds__(256) void nade_main(
    const float* __restrict__ x,      // [B,D]
    const float* __restrict__ Wt2,    // [D,H] transposed, scaled
    const float* __restrict__ prefix, // [B,C,H] exclusive prefix, scaled
    const float* __restrict__ bh,     // [H] (unscaled)
    const float* __restrict__ aw,     // [D,H]
    const float* __restrict__ ab,     // [D]
    float* __restrict__ llp,          // [B,C] partial log-likelihoods
    int Dn, int Hn, int Bn, int C, int L)
{
    const int gw   = blockIdx.x * 4 + (threadIdx.x >> 6);
    const int lane = threadIdx.x & 63;
    const int b = gw % Bn;           // c-major mapping
    const int c = gw / Bn;
    const float* xrow = x + (size_t)b * Dn;
    const int j = lane & 3;          // this lane's i-class within a 4-batch

    float4 bh2 = *(const float4*)(bh + lane * 4);
    bh2.x *= NLOG2E; bh2.y *= NLOG2E; bh2.z *= NLOG2E; bh2.w *= NLOG2E;

    float4 accw2 = *(const float4*)(prefix + ((size_t)b * C + c) * Hn + lane * 4);
    float i_f = (float)(c * L);      // global i (bias count), folded via fma

    float A = 0.f;                   // sum of lp*(2*x-1) over my i-class
    float Bs = 0.f;                  // sum of x over my i-class
    const int i0 = c * L;

    for (int i = i0; i < i0 + L; i += 4) {
        float p[4];
        const float xq  = xrow[i + j];   // per-lane: x for my i-class
        const float abq = ab[i + j];     // per-lane: alpha_bias for my i-class
#pragma unroll
        for (int m = 0; m < 4; ++m) {
            const float4 aw4 = *(const float4*)(aw  + (size_t)(i + m) * Hn + lane * 4);
            const float4 w4  = *(const float4*)(Wt2 + (size_t)(i + m) * Hn + lane * 4);
            // hidden uses state BEFORE update m (exclusive prefix)
            float u0 = __builtin_amdgcn_fmed3f(fmaf(i_f, bh2.x, accw2.x), -30.f, 30.f);
            float u1 = __builtin_amdgcn_fmed3f(fmaf(i_f, bh2.y, accw2.y), -30.f, 30.f);
            float u2 = __builtin_amdgcn_fmed3f(fmaf(i_f, bh2.z, accw2.z), -30.f, 30.f);
            float u3 = __builtin_amdgcn_fmed3f(fmaf(i_f, bh2.w, accw2.w), -30.f, 30.f);
            const float t0 = __builtin_amdgcn_exp2f(u0);
            const float t1 = __builtin_amdgcn_exp2f(u1);
            const float t2 = __builtin_amdgcn_exp2f(u2);
            const float t3 = __builtin_amdgcn_exp2f(u3);
            const float d0 = 1.0f + t0, d1 = 1.0f + t1;
            const float d2 = 1.0f + t2, d3 = 1.0f + t3;
            const float d01 = d0 * d1, d23 = d2 * d3;
            const float n01 = fmaf(aw4.y, d0, aw4.x * d1);
            const float n23 = fmaf(aw4.w, d2, aw4.z * d3);
            const float N   = fmaf(n23, d01, n01 * d23);
            const float D   = d01 * d23;
            p[m] = N * __builtin_amdgcn_rcpf(D);
            // state update (scaled domain, bias handled analytically via i_f)
            const float xv = xrow[i + m];
            accw2.x = fmaf(xv, w4.x, accw2.x);
            accw2.y = fmaf(xv, w4.y, accw2.y);
            accw2.z = fmaf(xv, w4.z, accw2.z);
            accw2.w = fmaf(xv, w4.w, accw2.w);
            i_f += 1.0f;
        }
        // reduce each p[m] within quads, select by class, butterfly quads
#pragma unroll
        for (int m = 0; m < 4; ++m) {
            p[m] += __shfl_xor(p[m], 1, 64);
            p[m] += __shfl_xor(p[m], 2, 64);
        }
        float t0 = (lane & 1) ? p[1] : p[0];
        float t1 = (lane & 1) ? p[3] : p[2];
        float q  = (lane & 2) ? t1 : t0;
        q += __shfl_xor(q, 4, 64);
        q += __shfl_xor(q, 8, 64);
        q += __shfl_xor(q, 16, 64);
        q += __shfl_xor(q, 32, 64);
        // q = full 256-h dot product for i + j (replicated over 16 lanes)
        const float s = q + abq;
        // lp = log(sigmoid(s)) = -ln(1 + e^-s)
        const float lp = -LN2 *
            __builtin_amdgcn_logf(1.0f + __builtin_amdgcn_exp2f(-s * LOG2E));
        // term = 2*x*lp - x - lp + 1 ; accumulate A=sum lp*(2x-1), B=sum x
        A = fmaf(lp, fmaf(2.0f, xq, -1.0f), A);
        Bs += xq;
    }

    // each class replicated 16x across the wave
#pragma unroll
    for (int off = 32; off > 0; off >>= 1) {
        A  += __shfl_xor(A, off, 64);
        Bs += __shfl_xor(Bs, off, 64);
    }
    if (lane == 0)
        llp[(size_t)b * C + c] = (A - Bs) * (1.0f / 16.0f) + (float)L;
}

// ---------- pass 4: final reduce ----------
__global__ void final_kernel(const float* __restrict__ llp,
                             float* __restrict__ out, int Bn, int C) {
    const int b = blockIdx.x * blockDim.x + threadIdx.x;
    if (b < Bn) {
        float s = 0.f;
        for (int c = 0; c < C; ++c) s += llp[(size_t)b * C + c];
        out[b] = s;
    }
}

// ---------- fallback (round-1 style, unscaled) ----------
__global__ __launch_bounds__(64) void nade_fallback(
    const float* __restrict__ x, const float* __restrict__ Wh,
    const float* __restrict__ bh, const float* __restrict__ aw,
    const float* __restrict__ ab, float* __restrict__ out, int Dn, int Hn)
{
    const int b    = blockIdx.x;
    const int lane = threadIdx.x;
    const float* xrow = x + (size_t)b * Dn;
    float ll = 0.f;
    float accl[8];
    float bhl[8];
    for (int k = 0; k < 8; ++k) { accl[k] = 0.f; bhl[k] = 0.f; }
    const int hper = Hn / 64;
    for (int k = 0; k < hper && k < 8; ++k) bhl[k] = bh[lane * hper + k];
    for (int i = 0; i < Dn; ++i) {
        float pm = 0.f;
        for (int k = 0; k < hper && k < 8; ++k) {
            const int h = lane * hper + k;
            const float sg = __builtin_amdgcn_rcpf(
                1.0f + __builtin_amdgcn_exp2f(-accl[k] * LOG2E));
            pm = fmaf(aw[(size_t)i * Hn + h], sg, pm);
        }
        for (int off = 32; off > 0; off >>= 1) pm += __shfl_xor(pm, off, 64);
        const float s = pm + ab[i];
        const float lp = -LN2 *
            __builtin_amdgcn_logf(1.0f + __builtin_amdgcn_exp2f(-s * LOG2E));
        const float xv = xrow[i];
        ll += xv * lp + (1.0f - xv) * (1.0f - lp);
        for (int k = 0; k < hper && k < 8; ++k) {
            const int h = lane * hper + k;
            accl[k] = fmaf(xv, Wh[(size_t)h * Dn + i], accl[k]) + bhl[k];
        }
    }
    if (lane == 0) out[b] = ll;
}

extern "C" void kernel_launch(void* const* d_in, const int* in_sizes, int n_in,
                              void* d_out, int out_size, void* d_ws, size_t ws_size,
                              hipStream_t stream) {
    const float* x  = (const float*)d_in[0];
    const float* Wh = (const float*)d_in[1];
    const float* bh = (const float*)d_in[2];
    const float* aw = (const float*)d_in[3];
    const float* ab = (const float*)d_in[4];
    float* out = (float*)d_out;

    const int Bn = out_size;          // 1024
    const int Hn = in_sizes[2];       // 256
    const int Dn = in_sizes[4];       // 1024
    const int C  = 8;
    const int L  = Dn / C;

    const size_t wt_bytes  = (size_t)Dn * Hn * sizeof(float);
    const size_t pf_bytes  = (size_t)Bn * C * Hn * sizeof(float);
    const size_t llp_bytes = (size_t)Bn * C * sizeof(float);

    const bool shapes_ok = (Hn == 256) && (Dn % (32 * C) == 0) && (L % 4 == 0) &&
                           (Bn % 4 == 0);
    const bool full_path = shapes_ok && ws_size >= wt_bytes + pf_bytes + llp_bytes;

    if (full_path) {
        float* Wt2    = (float*)d_ws;
        float* prefix = (float*)((char*)d_ws + wt_bytes);
        float* llp    = (float*)((char*)d_ws + wt_bytes + pf_bytes);

        transpose_kernel<<<dim3(Dn / 32, Hn / 32), dim3(32, 8), 0, stream>>>(
            Wh, Wt2, Hn, Dn, NLOG2E);
        partial_kernel<<<(Bn * C) / 4, 256, 0, stream>>>(
            x, Wt2, prefix, Dn, Hn, Bn, C, L);
        scan_kernel<<<Bn / 4, 256, 0, stream>>>(prefix, Hn, C);
        nade_main<<<(Bn * C) / 4, 256, 0, stream>>>(
            x, Wt2, prefix, bh, aw, ab, llp, Dn, Hn, Bn, C, L);
        final_kernel<<<(Bn + 255) / 256, 256, 0, stream>>>(llp, out, Bn, C);
    } else {
        nade_fallback<<<Bn, 64, 0, stream>>>(x, Wh, bh, aw, ab, out, Dn, Hn);
    }
}

// Round 5
// 134.774 us; speedup vs baseline: 2.6465x; 1.0442x over previous
//
#include <hip/hip_runtime.h>

#define LOG2E  1.44269504088896f
#define NLOG2E (-1.44269504088896f)
#define LN2    0.693147180559945f

// ---------- W_h [H,D] -> W_t [D,H] (pre-scaled by `scale`) ----------
__global__ void transpose_kernel(const float* __restrict__ Wh,
                                 float* __restrict__ Wt, int Hn, int Dn,
                                 float scale) {
    __shared__ float tile[32][33];
    int tx = threadIdx.x;        // 0..31
    int ty = threadIdx.y;        // 0..7
    int i0 = blockIdx.x * 32;    // D tile origin
    int h0 = blockIdx.y * 32;    // H tile origin
#pragma unroll
    for (int k = 0; k < 4; ++k)
        tile[ty + 8 * k][tx] = scale * Wh[(size_t)(h0 + ty + 8 * k) * Dn + (i0 + tx)];
    __syncthreads();
#pragma unroll
    for (int k = 0; k < 4; ++k)
        Wt[(size_t)(i0 + ty + 8 * k) * Hn + (h0 + tx)] = tile[tx][ty + 8 * k];
}

// ---------- pass 1: per-chunk partial x·W sums (scaled domain) ----------
__global__ __launch_bounds__(256) void partial_kernel(
    const float* __restrict__ x, const float* __restrict__ Wt,
    float* __restrict__ partial, int Dn, int Hn, int Bn, int C, int L)
{
    const int gw   = blockIdx.x * 4 + (threadIdx.x >> 6);
    const int lane = threadIdx.x & 63;
    const int b = gw % Bn;           // c-major: co-resident waves share rows
    const int c = gw / Bn;
    const float* xrow = x + (size_t)b * Dn;

    float4 acc = make_float4(0.f, 0.f, 0.f, 0.f);
    const int i0 = c * L;
#pragma unroll 4
    for (int i = i0; i < i0 + L; ++i) {
        const float xv = xrow[i];
        const float4 w4 = *(const float4*)(Wt + (size_t)i * Hn + lane * 4);
        acc.x += xv * w4.x;
        acc.y += xv * w4.y;
        acc.z += xv * w4.z;
        acc.w += xv * w4.w;
    }
    *(float4*)(partial + ((size_t)b * C + c) * Hn + lane * 4) = acc;
}

// ---------- pass 2: exclusive scan over chunks (in place) ----------
__global__ __launch_bounds__(256) void scan_kernel(
    float* __restrict__ partial, int Hn, int C)
{
    const int b    = blockIdx.x * 4 + (threadIdx.x >> 6);
    const int lane = threadIdx.x & 63;
    float* base = partial + (size_t)b * C * Hn + lane * 4;
    float4 acc = make_float4(0.f, 0.f, 0.f, 0.f);
    for (int c = 0; c < C; ++c) {
        float4 cur = *(float4*)(base + (size_t)c * Hn);
        *(float4*)(base + (size_t)c * Hn) = acc;
        acc.x += cur.x; acc.y += cur.y; acc.z += cur.z; acc.w += cur.w;
    }
}

// ---------- pass 3: main NADE chunk kernel ----------
// Scaled domain: Wt2 = -log2e * W^T, prefix likewise, bh2 = -log2e * b_h.
// State u_h = -log2e*(x-dot-prefix + i*b_h) maintained DIRECTLY:
//   sigma_h = rcp(1 + exp2(u_h));  u += xv*w + bh2  each step.
// No clamp needed: |u| <= ~96 so exp2/rcp saturate without overflow.
__global__ __launch_bounds__(256) void nade_main(
    const float* __restrict__ x,      // [B,D]
    const float* __restrict__ Wt2,    // [D,H] transposed, scaled
    const float* __restrict__ prefix, // [B,C,H] exclusive prefix, scaled
    const float* __restrict__ bh,     // [H] (unscaled)
    const float* __restrict__ aw,     // [D,H]
    const float* __restrict__ ab,     // [D]
    float* __restrict__ llp,          // [B,C] partial log-likelihoods
    int Dn, int Hn, int Bn, int C, int L)
{
    const int gw   = blockIdx.x * 4 + (threadIdx.x >> 6);
    const int lane = threadIdx.x & 63;
    const int b = gw % Bn;           // c-major mapping
    const int c = gw / Bn;
    const int j = lane & 3;          // this lane's i-class within a 4-batch

    float4 bh2 = *(const float4*)(bh + lane * 4);
    bh2.x *= NLOG2E; bh2.y *= NLOG2E; bh2.z *= NLOG2E; bh2.w *= NLOG2E;

    float4 u = *(const float4*)(prefix + ((size_t)b * C + c) * Hn + lane * 4);
    const float cl = (float)(c * L);
    u.x = fmaf(cl, bh2.x, u.x);
    u.y = fmaf(cl, bh2.y, u.y);
    u.z = fmaf(cl, bh2.z, u.z);
    u.w = fmaf(cl, bh2.w, u.w);

    // wave-uniform row pointers (SALU-advanced); per-lane fixed offset
    const int lo = lane * 4;
    const float* awp = aw  + (size_t)(c * L) * Hn;
    const float* wp  = Wt2 + (size_t)(c * L) * Hn;
    const float* xp  = x   + (size_t)b * Dn + c * L;
    const float* abp = ab  + c * L;

    float A  = 0.f;                  // sum of lp*(2*x-1) over my i-class
    float Bs = 0.f;                  // sum of x over my i-class

#pragma unroll 2
    for (int ii = 0; ii < L; ii += 4) {
        const float xq  = xp[ii + j];    // per-lane: x for my i-class
        const float abq = abp[ii + j];   // per-lane: alpha_bias for my i-class
        float p[4];
#pragma unroll
        for (int m = 0; m < 4; ++m) {
            // m*Hn folds into the 13-bit immediate offset (m*1024 B)
            const float4 aw4 = *(const float4*)(awp + lo + m * Hn);
            const float4 w4  = *(const float4*)(wp  + lo + m * Hn);
            const float  xv  = __shfl(xq, m, 4);   // DPP quad broadcast
            // hidden uses state BEFORE update m (exclusive prefix)
            const float s0 = __builtin_amdgcn_rcpf(1.0f + __builtin_amdgcn_exp2f(u.x));
            const float s1 = __builtin_amdgcn_rcpf(1.0f + __builtin_amdgcn_exp2f(u.y));
            const float s2 = __builtin_amdgcn_rcpf(1.0f + __builtin_amdgcn_exp2f(u.z));
            const float s3 = __builtin_amdgcn_rcpf(1.0f + __builtin_amdgcn_exp2f(u.w));
            float pm = aw4.x * s0;
            pm = fmaf(aw4.y, s1, pm);
            pm = fmaf(aw4.z, s2, pm);
            pm = fmaf(aw4.w, s3, pm);
            p[m] = pm;
            // state update (bias folded per-step)
            u.x += fmaf(xv, w4.x, bh2.x);
            u.y += fmaf(xv, w4.y, bh2.y);
            u.z += fmaf(xv, w4.z, bh2.z);
            u.w += fmaf(xv, w4.w, bh2.w);
        }
        awp += 4 * Hn;               // SALU pointer advance, once per 4-i
        wp  += 4 * Hn;

        // reduce each p[m] within quads, select by class, butterfly quads
#pragma unroll
        for (int m = 0; m < 4; ++m) {
            p[m] += __shfl_xor(p[m], 1, 64);
            p[m] += __shfl_xor(p[m], 2, 64);
        }
        float t0 = (lane & 1) ? p[1] : p[0];
        float t1 = (lane & 1) ? p[3] : p[2];
        float q  = (lane & 2) ? t1 : t0;
        q += __shfl_xor(q, 4, 64);
        q += __shfl_xor(q, 8, 64);
        q += __shfl_xor(q, 16, 64);
        q += __shfl_xor(q, 32, 64);
        // q = full 256-h dot product for i + j (replicated over 16 lanes)
        const float s = q + abq;
        // lp = log(sigmoid(s)) = -ln(1 + e^-s)
        const float lp = -LN2 *
            __builtin_amdgcn_logf(1.0f + __builtin_amdgcn_exp2f(-s * LOG2E));
        // term = 2*x*lp - x - lp + 1 ; accumulate A=sum lp*(2x-1), B=sum x
        A = fmaf(lp, fmaf(2.0f, xq, -1.0f), A);
        Bs += xq;
    }

    // each class replicated 16x across the wave
#pragma unroll
    for (int off = 32; off > 0; off >>= 1) {
        A  += __shfl_xor(A, off, 64);
        Bs += __shfl_xor(Bs, off, 64);
    }
    if (lane == 0)
        llp[(size_t)b * C + c] = (A - Bs) * (1.0f / 16.0f) + (float)L;
}

// ---------- pass 4: final reduce ----------
__global__ void final_kernel(const float* __restrict__ llp,
                             float* __restrict__ out, int Bn, int C) {
    const int b = blockIdx.x * blockDim.x + threadIdx.x;
    if (b < Bn) {
        float s = 0.f;
        for (int c = 0; c < C; ++c) s += llp[(size_t)b * C + c];
        out[b] = s;
    }
}

// ---------- fallback (round-1 style, unscaled) ----------
__global__ __launch_bounds__(64) void nade_fallback(
    const float* __restrict__ x, const float* __restrict__ Wh,
    const float* __restrict__ bh, const float* __restrict__ aw,
    const float* __restrict__ ab, float* __restrict__ out, int Dn, int Hn)
{
    const int b    = blockIdx.x;
    const int lane = threadIdx.x;
    const float* xrow = x + (size_t)b * Dn;
    float ll = 0.f;
    float accl[8];
    float bhl[8];
    for (int k = 0; k < 8; ++k) { accl[k] = 0.f; bhl[k] = 0.f; }
    const int hper = Hn / 64;
    for (int k = 0; k < hper && k < 8; ++k) bhl[k] = bh[lane * hper + k];
    for (int i = 0; i < Dn; ++i) {
        float pm = 0.f;
        for (int k = 0; k < hper && k < 8; ++k) {
            const int h = lane * hper + k;
            const float sg = __builtin_amdgcn_rcpf(
                1.0f + __builtin_amdgcn_exp2f(-accl[k] * LOG2E));
            pm = fmaf(aw[(size_t)i * Hn + h], sg, pm);
        }
        for (int off = 32; off > 0; off >>= 1) pm += __shfl_xor(pm, off, 64);
        const float s = pm + ab[i];
        const float lp = -LN2 *
            __builtin_amdgcn_logf(1.0f + __builtin_amdgcn_exp2f(-s * LOG2E));
        const float xv = xrow[i];
        ll += xv * lp + (1.0f - xv) * (1.0f - lp);
        for (int k = 0; k < hper && k < 8; ++k) {
            const int h = lane * hper + k;
            accl[k] = fmaf(xv, Wh[(size_t)h * Dn + i], accl[k]) + bhl[k];
        }
    }
    if (lane == 0) out[b] = ll;
}

extern "C" void kernel_launch(void* const* d_in, const int* in_sizes, int n_in,
                              void* d_out, int out_size, void* d_ws, size_t ws_size,
                              hipStream_t stream) {
    const float* x  = (const float*)d_in[0];
    const float* Wh = (const float*)d_in[1];
    const float* bh = (const float*)d_in[2];
    const float* aw = (const float*)d_in[3];
    const float* ab = (const float*)d_in[4];
    float* out = (float*)d_out;

    const int Bn = out_size;          // 1024
    const int Hn = in_sizes[2];       // 256
    const int Dn = in_sizes[4];       // 1024
    const int C  = 8;
    const int L  = Dn / C;

    const size_t wt_bytes  = (size_t)Dn * Hn * sizeof(float);
    const size_t pf_bytes  = (size_t)Bn * C * Hn * sizeof(float);
    const size_t llp_bytes = (size_t)Bn * C * sizeof(float);

    const bool shapes_ok = (Hn == 256) && (Dn % (32 * C) == 0) && (L % 8 == 0) &&
                           (Bn % 4 == 0);
    const bool full_path = shapes_ok && ws_size >= wt_bytes + pf_bytes + llp_bytes;

    if (full_path) {
        float* Wt2    = (float*)d_ws;
        float* prefix = (float*)((char*)d_ws + wt_bytes);
        float* llp    = (float*)((char*)d_ws + wt_bytes + pf_bytes);

        transpose_kernel<<<dim3(Dn / 32, Hn / 32), dim3(32, 8), 0, stream>>>(
            Wh, Wt2, Hn, Dn, NLOG2E);
        partial_kernel<<<(Bn * C) / 4, 256, 0, stream>>>(
            x, Wt2, prefix, Dn, Hn, Bn, C, L);
        scan_kernel<<<Bn / 4, 256, 0, stream>>>(prefix, Hn, C);
        nade_main<<<(Bn * C) / 4, 256, 0, stream>>>(
            x, Wt2, prefix, bh, aw, ab, llp, Dn, Hn, Bn, C, L);
        final_kernel<<<(Bn + 255) / 256, 256, 0, stream>>>(llp, out, Bn, C);
    } else {
        nade_fallback<<<Bn, 64, 0, stream>>>(x, Wh, bh, aw, ab, out, Dn, Hn);
    }
}